// Round 1
// baseline (8996.950 us; speedup 1.0000x reference)
//
#include <hip/hip_runtime.h>
#include <stdint.h>

#define DEVINL __device__ __forceinline__

typedef __attribute__((ext_vector_type(8))) __bf16 bf16x8;
typedef __attribute__((ext_vector_type(8))) unsigned short ushort8;
typedef __attribute__((ext_vector_type(4))) float floatx4;

constexpr int E_ = 256;
constexpr int TAGS = 22, ST_START = 20, ST_STOP = 21;
constexpr int B_ = 128, S_ = 256, BS_ = B_ * S_;
constexpr int NG = 1024;  // 4*H

DEVINL uint16_t f2bf(float f) {  // RNE f32->bf16 (no NaN inputs expected)
  uint32_t u = __builtin_bit_cast(uint32_t, f);
  return (uint16_t)((u + 0x7fffu + ((u >> 16) & 1u)) >> 16);
}
DEVINL float bf2f(uint16_t h) {
  uint32_t u = ((uint32_t)h) << 16;
  return __builtin_bit_cast(float, u);
}
DEVINL uint4 pack8(float4 a, float4 b) {
  ushort8 h;
  h[0] = f2bf(a.x); h[1] = f2bf(a.y); h[2] = f2bf(a.z); h[3] = f2bf(a.w);
  h[4] = f2bf(b.x); h[5] = f2bf(b.y); h[6] = f2bf(b.z); h[7] = f2bf(b.w);
  return __builtin_bit_cast(uint4, h);
}
DEVINL floatx4 mfma16(uint4 a, uint4 b, floatx4 c) {
  return __builtin_amdgcn_mfma_f32_16x16x32_bf16(
      __builtin_bit_cast(bf16x8, a), __builtin_bit_cast(bf16x8, b), c, 0, 0, 0);
}
DEVINL float sigf(float x) { return 1.f / (1.f + __expf(-x)); }
// tanh via exp; saturates cleanly at +-1 for |x| large (no inf/inf NaN).
DEVINL float tanh_(float x) { return 1.f - 2.f / (__expf(2.f * x) + 1.f); }

// ---------------- init: zero output + sync flags (ws is poisoned 0xAA) ----------
__global__ void k_init(float* out, int out_n, int* flags) {
  int t = threadIdx.x;
  if (t < out_n) out[t] = 0.f;
  if (t < 64) flags[t] = 0;
}

// ---------------- f32 -> bf16 weight conversion ----------------
__global__ void k_f2bf(const float* __restrict__ src, uint16_t* __restrict__ dst, int n) {
  int i = blockIdx.x * blockDim.x + threadIdx.x;
  int stride = gridDim.x * blockDim.x;
  for (; i < n; i += stride) dst[i] = f2bf(src[i]);
}

// ---------------- xg GEMM: out[m, ng] = A[m,:] . wb[ng,:]  (ng = dir*1024+n) ----
// A: EMBED ? embedding[word[m]] (f32 gather) : xa (bf16 [32768][K])
// out layout: xg[dir][m][1024] bf16
template <bool EMBED, int K>
__global__ __launch_bounds__(256) void k_gemm(
    const float* __restrict__ emb, const int* __restrict__ word,
    const uint16_t* __restrict__ xa, const uint16_t* __restrict__ wb,
    uint16_t* __restrict__ xg) {
  __shared__ uint4 As[8 * 128];  // [k8][m][8] bf16, 16KB
  __shared__ uint4 Bs[8 * 128];  // [k8][n][8] bf16, 16KB
  const int tid = threadIdx.x;
  const int bx = blockIdx.x;
  const int m0 = (bx & 255) << 7;
  const int n0 = (bx >> 8) << 7;
  const int lane = tid & 63, w = tid >> 6;
  const int ln = lane & 15, q = lane >> 4;
  const int wm = w & 1, wn = w >> 1;

  floatx4 acc[4][4];
#pragma unroll
  for (int a = 0; a < 4; a++)
#pragma unroll
    for (int b = 0; b < 4; b++) acc[a][b] = (floatx4){0.f, 0.f, 0.f, 0.f};

  for (int k0 = 0; k0 < K; k0 += 64) {
#pragma unroll
    for (int it = 0; it < 4; it++) {
      int c = tid + it * 256;  // 0..1023
      int k8 = c & 7, r = c >> 3;
      if (EMBED) {
        int row = word[m0 + r];
        const float* sp = emb + (size_t)row * E_ + k0 + k8 * 8;
        float4 f0 = *(const float4*)sp;
        float4 f1 = *(const float4*)(sp + 4);
        As[k8 * 128 + r] = pack8(f0, f1);
      } else {
        As[k8 * 128 + r] = *(const uint4*)(xa + (size_t)(m0 + r) * K + k0 + k8 * 8);
      }
      Bs[k8 * 128 + r] = *(const uint4*)(wb + (size_t)(n0 + r) * K + k0 + k8 * 8);
    }
    __syncthreads();
#pragma unroll
    for (int kk = 0; kk < 2; kk++) {
      const int k4b = kk * 4 + q;
      uint4 af[4], bf[4];
#pragma unroll
      for (int mt = 0; mt < 4; mt++) af[mt] = As[k4b * 128 + wm * 64 + mt * 16 + ln];
#pragma unroll
      for (int nt = 0; nt < 4; nt++) bf[nt] = Bs[k4b * 128 + wn * 64 + nt * 16 + ln];
#pragma unroll
      for (int mt = 0; mt < 4; mt++)
#pragma unroll
        for (int nt = 0; nt < 4; nt++) acc[mt][nt] = mfma16(af[mt], bf[nt], acc[mt][nt]);
    }
    __syncthreads();
  }
  // epilogue: C/D layout col=lane&15, row=q*4+reg
#pragma unroll
  for (int mt = 0; mt < 4; mt++) {
    int Rb = m0 + wm * 64 + mt * 16 + q * 4;
#pragma unroll
    for (int nt = 0; nt < 4; nt++) {
      int C = n0 + wn * 64 + nt * 16 + ln;
      size_t base = (size_t)(C >> 10) * ((size_t)BS_ * NG) + (C & 1023);
#pragma unroll
      for (int r = 0; r < 4; r++) xg[base + (size_t)(Rb + r) * NG] = f2bf(acc[mt][nt][r]);
    }
  }
}

// ---------------- BiLSTM recurrence (one layer, both dirs) ----------------
// 256 WGs x 256 thr. group = (dir, batch-tile of 16), 16 members each owning 16 h-cols
// (64 gate rows). w_hh slice lives in LDS; h exchanged via global hbuf + flag counter.
__global__ __launch_bounds__(256) void k_rec(
    const uint16_t* __restrict__ xg, const float* __restrict__ w_hh,
    const float* __restrict__ b_ih, const float* __restrict__ b_hh,
    uint16_t* __restrict__ xout, uint16_t* __restrict__ hbuf,
    int* __restrict__ flags) {
  __shared__ uint4 Wl[32 * 64];     // B-frag layout [k4][n][8] bf16, 32KB
  __shared__ uint4 hA[512];         // A-frag layout [k4][m][8] bf16, 8KB
  __shared__ float gates[16 * 68];  // [m][64 gate cols], padded stride 68
  __shared__ float bias_s[64];

  const int tid = threadIdx.x;
  const int wg = blockIdx.x;
  const int group = wg & 15, member = wg >> 4;
  const int dir = group & 1, tile = group >> 1;
  const int j0 = member * 16;
  const int lane = tid & 63, w = tid >> 6, ln = lane & 15, q = lane >> 4;

  // stage w_hh slice -> LDS (bf16, B-fragment layout)
  for (int p = tid; p < 2048; p += 256) {
    int n = p & 63, k4 = p >> 6;
    int row = dir * 1024 + (n >> 4) * 256 + j0 + (n & 15);  // gate g=n>>4, col j0+(n&15)
    const float* sp = w_hh + (size_t)row * 256 + k4 * 8;
    float4 f0 = *(const float4*)sp;
    float4 f1 = *(const float4*)(sp + 4);
    Wl[k4 * 64 + n] = pack8(f0, f1);
  }
  if (tid < 64) {
    int row = dir * 1024 + (tid >> 4) * 256 + j0 + (tid & 15);
    bias_s[tid] = b_ih[row] + b_hh[row];
  }
  __syncthreads();

  const int nloc = w * 16 + ln;                          // local gate col 0..63
  const int nglob = (nloc >> 4) * 256 + j0 + (nloc & 15);  // col in [0,1024)
  const float breg = bias_s[nloc];
  const uint16_t* xgd = xg + (size_t)dir * BS_ * NG;

  const int ms = tid & 15, js = tid >> 4;  // this thread's (m, j) state
  const int kj = j0 + js;                  // global h index (= K index next step)
  const int hb_idx = (kj >> 3) * 128 + ms * 8 + (kj & 7);
  const size_t xo_off = (size_t)(tile * 16 + ms) * 256 * 512 + dir * 256 + kj;
  float c_st = 0.f;

  for (int t = 0; t < 256; t++) {
    const int sg = dir ? (255 - t) : t;
    floatx4 acc = (floatx4){0.f, 0.f, 0.f, 0.f};
    if (t > 0) {
      const uint4* hsrc =
          (const uint4*)hbuf + (size_t)((((t - 1) & 1) * 16) + dir * 8 + tile) * 512;
      hA[tid] = hsrc[tid];
      hA[tid + 256] = hsrc[tid + 256];
      __syncthreads();
#pragma unroll
      for (int kk = 0; kk < 8; kk++) {
        int k4b = kk * 4 + q;
        acc = mfma16(hA[k4b * 16 + ln], Wl[k4b * 64 + nloc], acc);
      }
    }
    // gate preactivation: W*h + x_t@w_ih (precomputed) + (b_ih+b_hh)
#pragma unroll
    for (int r = 0; r < 4; r++) {
      int m = q * 4 + r;
      float xv = bf2f(xgd[(size_t)((tile * 16 + m) * 256 + sg) * NG + nglob]);
      gates[m * 68 + nloc] = acc[r] + xv + breg;
    }
    __syncthreads();
    // state update (gate order i,f,g,o)
    float ig = gates[ms * 68 + js];
    float fg = gates[ms * 68 + 16 + js];
    float gg = gates[ms * 68 + 32 + js];
    float og = gates[ms * 68 + 48 + js];
    c_st = sigf(fg) * c_st + sigf(ig) * tanh_(gg);
    float h = sigf(og) * tanh_(c_st);
    uint16_t hb = f2bf(h);
    xout[xo_off + (size_t)sg * 512] = hb;
    hbuf[(size_t)(((t & 1) * 16) + dir * 8 + tile) * 4096 + hb_idx] = hb;
    __syncthreads();  // drains vmcnt: all WG stores done before release
    if (t < 255) {
      if (tid == 0) {
        __hip_atomic_fetch_add(&flags[group], 1, __ATOMIC_RELEASE, __HIP_MEMORY_SCOPE_AGENT);
        int want = 16 * (t + 1);
        while (__hip_atomic_load(&flags[group], __ATOMIC_ACQUIRE, __HIP_MEMORY_SCOPE_AGENT) <
               want) {
        }
      }
      __syncthreads();
    }
  }
}

// ---------------- LayerNorm + projection to 22 tags ----------------
__global__ __launch_bounds__(256) void k_lnproj(
    const uint16_t* __restrict__ x2, const float* __restrict__ ln_g,
    const float* __restrict__ ln_b, const float* __restrict__ w_out,
    const float* __restrict__ b_out, float* __restrict__ feats) {
  const int w = threadIdx.x >> 6, lane = threadIdx.x & 63;
  const int row = blockIdx.x * 4 + w;
  ushort8 xu = __builtin_bit_cast(ushort8, *((const uint4*)(x2 + (size_t)row * 512) + lane));
  float f[8];
  float s = 0.f, ss = 0.f;
#pragma unroll
  for (int j = 0; j < 8; j++) {
    f[j] = bf2f(xu[j]);
    s += f[j];
    ss += f[j] * f[j];
  }
#pragma unroll
  for (int o = 1; o < 64; o <<= 1) {
    s += __shfl_xor(s, o, 64);
    ss += __shfl_xor(ss, o, 64);
  }
  float mu = s * (1.f / 512.f);
  float var = ss * (1.f / 512.f) - mu * mu;
  float rs = rsqrtf(var + 1e-5f);
  const float4 g0 = *(const float4*)(ln_g + lane * 8);
  const float4 g1 = *(const float4*)(ln_g + lane * 8 + 4);
  const float4 bb0 = *(const float4*)(ln_b + lane * 8);
  const float4 bb1 = *(const float4*)(ln_b + lane * 8 + 4);
  float gl[8] = {g0.x, g0.y, g0.z, g0.w, g1.x, g1.y, g1.z, g1.w};
  float bl[8] = {bb0.x, bb0.y, bb0.z, bb0.w, bb1.x, bb1.y, bb1.z, bb1.w};
  float xh[8];
#pragma unroll
  for (int j = 0; j < 8; j++) xh[j] = (f[j] - mu) * rs * gl[j] + bl[j];
  float* fr = feats + (size_t)row * TAGS;
  for (int tg = 0; tg < TAGS; tg++) {
    const float4 w0 = *(const float4*)(w_out + tg * 512 + lane * 8);
    const float4 w1 = *(const float4*)(w_out + tg * 512 + lane * 8 + 4);
    float p = xh[0] * w0.x + xh[1] * w0.y + xh[2] * w0.z + xh[3] * w0.w + xh[4] * w1.x +
              xh[5] * w1.y + xh[6] * w1.z + xh[7] * w1.w;
#pragma unroll
    for (int o = 1; o < 64; o <<= 1) p += __shfl_xor(p, o, 64);
    if (lane == 0) fr[tg] = p + b_out[tg];
  }
}

// ---------------- CRF NLL: one wave per batch row ----------------
__global__ __launch_bounds__(64) void k_crf(
    const float* __restrict__ feats, const float* __restrict__ trans,
    const int* __restrict__ mask, const int* __restrict__ tags, float* __restrict__ out) {
  const int b = blockIdx.x, j = threadIdx.x;
  const bool act = j < TAGS;
  float tcol[TAGS];
#pragma unroll
  for (int i = 0; i < TAGS; i++) tcol[i] = act ? trans[i * TAGS + j] : 0.f;
  const float tstop = act ? trans[j * TAGS + ST_STOP] : 0.f;
  const float* fb = feats + (size_t)b * 256 * TAGS;
  const int* mb = mask + b * 256;
  const int* tb = tags + b * 256;
  float alpha = act ? (tcol[ST_START] + fb[j]) : -1e30f;
  for (int t = 1; t < 256; t++) {
    float vv[TAGS];
    float mx = -1e30f;
#pragma unroll
    for (int i = 0; i < TAGS; i++) {
      float v = __shfl(alpha, i, 64) + tcol[i];
      vv[i] = v;
      mx = fmaxf(mx, v);
    }
    float s = 0.f;
#pragma unroll
    for (int i = 0; i < TAGS; i++) s += __expf(vv[i] - mx);
    float nw = mx + __logf(s) + (act ? fb[t * TAGS + j] : 0.f);
    if (act && mb[t] > 0) alpha = nw;
  }
  float z = act ? (alpha + tstop) : -1e30f;
  float mz = z;
#pragma unroll
  for (int o = 1; o < 64; o <<= 1) mz = fmaxf(mz, __shfl_xor(mz, o, 64));
  float se = act ? __expf(z - mz) : 0.f;
#pragma unroll
  for (int o = 1; o < 64; o <<= 1) se += __shfl_xor(se, o, 64);
  float logZ = mz + __logf(se);
  // emit score + mask count
  float em = 0.f;
  int cnt = 0;
  for (int tt = j; tt < 256; tt += 64) {
    int m = mb[tt];
    cnt += m;
    if (m > 0) em += fb[tt * TAGS + tb[tt]];
  }
#pragma unroll
  for (int o = 1; o < 64; o <<= 1) {
    em += __shfl_xor(em, o, 64);
    cnt += __shfl_xor(cnt, o, 64);
  }
  // transition score
  float tr = 0.f;
  for (int tt = 1 + j; tt < 256; tt += 64)
    if (mb[tt] > 0) tr += trans[tb[tt - 1] * TAGS + tb[tt]];
#pragma unroll
  for (int o = 1; o < 64; o <<= 1) tr += __shfl_xor(tr, o, 64);
  if (j == 0) {
    tr += trans[ST_START * TAGS + tb[0]];
    int last = cnt - 1;
    tr += trans[tb[last] * TAGS + ST_STOP];
    atomicAdd(out, (logZ - em - tr) * (1.f / 128.f));
  }
}

extern "C" void kernel_launch(void* const* d_in, const int* in_sizes, int n_in, void* d_out,
                              int out_size, void* d_ws, size_t ws_size, hipStream_t stream) {
  (void)in_sizes;
  (void)n_in;
  const float* emb = (const float*)d_in[0];
  const float* w_ih0 = (const float*)d_in[1];
  const float* w_hh0 = (const float*)d_in[2];
  const float* b_ih0 = (const float*)d_in[3];
  const float* b_hh0 = (const float*)d_in[4];
  const float* w_ih1 = (const float*)d_in[5];
  const float* w_hh1 = (const float*)d_in[6];
  const float* b_ih1 = (const float*)d_in[7];
  const float* b_hh1 = (const float*)d_in[8];
  const float* ln_g = (const float*)d_in[9];
  const float* ln_b = (const float*)d_in[10];
  const float* w_out = (const float*)d_in[11];
  const float* b_out = (const float*)d_in[12];
  const float* trans = (const float*)d_in[13];
  const int* word = (const int*)d_in[14];
  const int* mask = (const int*)d_in[15];
  const int* tags = (const int*)d_in[16];

  char* ws = (char*)d_ws;
  size_t off = 0;
  auto take = [&](size_t bytes) -> char* {
    char* p = ws + off;
    off = (off + bytes + 255) & ~(size_t)255;
    return p;
  };
  uint16_t* wb0 = (uint16_t*)take((size_t)2048 * 256 * 2);
  uint16_t* wb1 = (uint16_t*)take((size_t)2048 * 512 * 2);
  uint16_t* xg = (uint16_t*)take((size_t)2 * BS_ * 1024 * 2);
  uint16_t* x1 = (uint16_t*)take((size_t)BS_ * 512 * 2);  // layer0 out; reused as layer1 out
  float* feats = (float*)take((size_t)BS_ * TAGS * 4);
  uint16_t* hbuf = (uint16_t*)take((size_t)2 * 2 * 8 * 4096 * 2);
  int* flags = (int*)take(64 * 4);
  if (off > ws_size) return;  // insufficient workspace: fail loudly (poison stays)
  float* out = (float*)d_out;

  hipLaunchKernelGGL(k_init, dim3(1), dim3(256), 0, stream, out, out_size, flags);
  hipLaunchKernelGGL(k_f2bf, dim3(512), dim3(256), 0, stream, w_ih0, wb0, 2048 * 256);
  hipLaunchKernelGGL(k_f2bf, dim3(512), dim3(256), 0, stream, w_ih1, wb1, 2048 * 512);
  // layer 0
  hipLaunchKernelGGL((k_gemm<true, 256>), dim3(4096), dim3(256), 0, stream, emb, word,
                     (const uint16_t*)nullptr, wb0, xg);
  hipLaunchKernelGGL(k_rec, dim3(256), dim3(256), 0, stream, xg, w_hh0, b_ih0, b_hh0, x1, hbuf,
                     flags);
  // layer 1
  hipLaunchKernelGGL((k_gemm<false, 512>), dim3(4096), dim3(256), 0, stream,
                     (const float*)nullptr, (const int*)nullptr, x1, wb1, xg);
  hipLaunchKernelGGL(k_rec, dim3(256), dim3(256), 0, stream, xg, w_hh1, b_ih1, b_hh1, x1, hbuf,
                     flags + 16);
  // head
  hipLaunchKernelGGL(k_lnproj, dim3(8192), dim3(256), 0, stream, x1, ln_g, ln_b, w_out, b_out,
                     feats);
  hipLaunchKernelGGL(k_crf, dim3(128), dim3(64), 0, stream, feats, trans, mask, tags, out);
}

// Round 2
// 6039.750 us; speedup vs baseline: 1.4896x; 1.4896x over previous
//
#include <hip/hip_runtime.h>
#include <stdint.h>

#define DEVINL __device__ __forceinline__

typedef __attribute__((ext_vector_type(8))) __bf16 bf16x8;
typedef __attribute__((ext_vector_type(8))) unsigned short ushort8;
typedef __attribute__((ext_vector_type(4))) float floatx4;

constexpr int E_ = 256;
constexpr int TAGS = 22, ST_START = 20, ST_STOP = 21;
constexpr int B_ = 128, S_ = 256, BS_ = B_ * S_;
constexpr int NG = 1024;  // 4*H

DEVINL uint16_t f2bf(float f) {  // RNE f32->bf16 (no NaN inputs expected)
  uint32_t u = __builtin_bit_cast(uint32_t, f);
  return (uint16_t)((u + 0x7fffu + ((u >> 16) & 1u)) >> 16);
}
DEVINL float bf2f(uint16_t h) {
  uint32_t u = ((uint32_t)h) << 16;
  return __builtin_bit_cast(float, u);
}
DEVINL uint4 pack8(float4 a, float4 b) {
  ushort8 h;
  h[0] = f2bf(a.x); h[1] = f2bf(a.y); h[2] = f2bf(a.z); h[3] = f2bf(a.w);
  h[4] = f2bf(b.x); h[5] = f2bf(b.y); h[6] = f2bf(b.z); h[7] = f2bf(b.w);
  return __builtin_bit_cast(uint4, h);
}
DEVINL floatx4 mfma16(uint4 a, uint4 b, floatx4 c) {
  return __builtin_amdgcn_mfma_f32_16x16x32_bf16(
      __builtin_bit_cast(bf16x8, a), __builtin_bit_cast(bf16x8, b), c, 0, 0, 0);
}
DEVINL float sigf(float x) { return 1.f / (1.f + __expf(-x)); }
DEVINL float tanh_(float x) { return 1.f - 2.f / (__expf(2.f * x) + 1.f); }

// ---------------- init: zero output + sync flags (ws is poisoned 0xAA) ----------
__global__ void k_init(float* out, int out_n, int* flags) {
  int t = threadIdx.x;
  if (t < out_n) out[t] = 0.f;
  for (int i = t; i < 512; i += 256) flags[i] = 0;
}

// ---------------- f32 -> bf16 weight conversion ----------------
__global__ void k_f2bf(const float* __restrict__ src, uint16_t* __restrict__ dst, int n) {
  int i = blockIdx.x * blockDim.x + threadIdx.x;
  int stride = gridDim.x * blockDim.x;
  for (; i < n; i += stride) dst[i] = f2bf(src[i]);
}

// ---------------- xg GEMM: out[m, ng] = A[m,:] . wb[ng,:]  (ng = dir*1024+n) ----
template <bool EMBED, int K>
__global__ __launch_bounds__(256) void k_gemm(
    const float* __restrict__ emb, const int* __restrict__ word,
    const uint16_t* __restrict__ xa, const uint16_t* __restrict__ wb,
    uint16_t* __restrict__ xg) {
  __shared__ uint4 As[8 * 128];  // [k8][m][8] bf16, 16KB
  __shared__ uint4 Bs[8 * 128];  // [k8][n][8] bf16, 16KB
  const int tid = threadIdx.x;
  const int bx = blockIdx.x;
  const int m0 = (bx & 255) << 7;
  const int n0 = (bx >> 8) << 7;
  const int lane = tid & 63, w = tid >> 6;
  const int ln = lane & 15, q = lane >> 4;
  const int wm = w & 1, wn = w >> 1;

  floatx4 acc[4][4];
#pragma unroll
  for (int a = 0; a < 4; a++)
#pragma unroll
    for (int b = 0; b < 4; b++) acc[a][b] = (floatx4){0.f, 0.f, 0.f, 0.f};

  for (int k0 = 0; k0 < K; k0 += 64) {
#pragma unroll
    for (int it = 0; it < 4; it++) {
      int c = tid + it * 256;  // 0..1023
      int k8 = c & 7, r = c >> 3;
      if (EMBED) {
        int row = word[m0 + r];
        const float* sp = emb + (size_t)row * E_ + k0 + k8 * 8;
        float4 f0 = *(const float4*)sp;
        float4 f1 = *(const float4*)(sp + 4);
        As[k8 * 128 + r] = pack8(f0, f1);
      } else {
        As[k8 * 128 + r] = *(const uint4*)(xa + (size_t)(m0 + r) * K + k0 + k8 * 8);
      }
      Bs[k8 * 128 + r] = *(const uint4*)(wb + (size_t)(n0 + r) * K + k0 + k8 * 8);
    }
    __syncthreads();
#pragma unroll
    for (int kk = 0; kk < 2; kk++) {
      const int k4b = kk * 4 + q;
      uint4 af[4], bf[4];
#pragma unroll
      for (int mt = 0; mt < 4; mt++) af[mt] = As[k4b * 128 + wm * 64 + mt * 16 + ln];
#pragma unroll
      for (int nt = 0; nt < 4; nt++) bf[nt] = Bs[k4b * 128 + wn * 64 + nt * 16 + ln];
#pragma unroll
      for (int mt = 0; mt < 4; mt++)
#pragma unroll
        for (int nt = 0; nt < 4; nt++) acc[mt][nt] = mfma16(af[mt], bf[nt], acc[mt][nt]);
    }
    __syncthreads();
  }
#pragma unroll
  for (int mt = 0; mt < 4; mt++) {
    int Rb = m0 + wm * 64 + mt * 16 + q * 4;
#pragma unroll
    for (int nt = 0; nt < 4; nt++) {
      int C = n0 + wn * 64 + nt * 16 + ln;
      size_t base = (size_t)(C >> 10) * ((size_t)BS_ * NG) + (C & 1023);
#pragma unroll
      for (int r = 0; r < 4; r++) xg[base + (size_t)(Rb + r) * NG] = f2bf(acc[mt][nt][r]);
    }
  }
}

// ---------------- BiLSTM recurrence (one layer, both dirs) ----------------
// 128 WGs x 256 thr. group = (dir, batch-tile of 32) -> 8 groups, 16 members each
// owning 16 h-cols (64 gate rows, 32KB LDS). h exchanged via global hbuf (L2) +
// per-member epoch flags (padded cacheline per group, store-release / sleep-poll).
__global__ __launch_bounds__(256) void k_rec(
    const uint16_t* __restrict__ xg, const float* __restrict__ w_hh,
    const float* __restrict__ b_ih, const float* __restrict__ b_hh,
    uint16_t* __restrict__ xout, uint16_t* __restrict__ hbuf,
    int* __restrict__ flags) {
  __shared__ uint4 Wl[32 * 64];     // B-frag layout [k4][n=64], 32KB
  __shared__ uint4 hA[32 * 32];     // A-frag layout [k4][m=32], 16KB
  __shared__ float gates[32 * 68];  // [m][64 gate cols], padded stride 68
  __shared__ float bias_s[64];

  const int tid = threadIdx.x;
  const int wg = blockIdx.x;
  const int group = wg & 7, member = wg >> 3;  // 8 groups x 16 members
  const int dir = group & 1, tile = group >> 1;  // 4 tiles of 32 rows
  const int j0 = member * 16;
  const int lane = tid & 63, w = tid >> 6, ln = lane & 15, q = lane >> 4;

  // stage w_hh slice -> LDS (bf16, B-fragment layout). col n -> gate g=n>>4, j=j0+(n&15)
  for (int p = tid; p < 2048; p += 256) {
    int n = p & 63, k4 = p >> 6;
    int row = dir * 1024 + (n >> 4) * 256 + j0 + (n & 15);
    const float* sp = w_hh + (size_t)row * 256 + k4 * 8;
    float4 f0 = *(const float4*)sp;
    float4 f1 = *(const float4*)(sp + 4);
    Wl[k4 * 64 + n] = pack8(f0, f1);
  }
  if (tid < 64) {
    int row = dir * 1024 + (tid >> 4) * 256 + j0 + (tid & 15);
    bias_s[tid] = b_ih[row] + b_hh[row];
  }
  __syncthreads();

  const int nloc = w * 16 + ln;                            // gate col 0..63 (gate = w)
  const int nglob = w * 256 + j0 + ln;                     // col in [0,1024)
  const float breg = bias_s[nloc];
  const uint16_t* xgd = xg + (size_t)dir * BS_ * NG;

  const int ms = tid & 15, js = tid >> 4;  // state thread: rows {ms, ms+16}, col j0+js
  const int kj = j0 + js;
  const int hb_lo = (kj >> 3) * 256 + ms * 8 + (kj & 7);
  const int hb_hi = hb_lo + 16 * 8;
  const int fbase = group * 32;
  float c0 = 0.f, c1 = 0.f;

  // rows this thread's MFMA accs cover (for xg prefetch)
  const int xr0 = tile * 32 + q * 4;  // acc0 rows xr0..xr0+3 ; acc1 rows +16
  int sg = dir ? 255 : 0;
  uint16_t xv[8];
#pragma unroll
  for (int r = 0; r < 4; r++) {
    xv[r] = xgd[(size_t)((xr0 + r) * 256 + sg) * NG + nglob];
    xv[4 + r] = xgd[(size_t)((xr0 + 16 + r) * 256 + sg) * NG + nglob];
  }

  for (int t = 0; t < 256; t++) {
    sg = dir ? (255 - t) : t;
    floatx4 acc0 = (floatx4){0.f, 0.f, 0.f, 0.f};
    floatx4 acc1 = (floatx4){0.f, 0.f, 0.f, 0.f};
    if (t > 0) {
      // wait for all members' epoch >= t (h(t-1) published)
      if (tid < 64) {
        const int fidx = fbase + (tid & 15);
        int v = __hip_atomic_load(&flags[fidx], __ATOMIC_RELAXED, __HIP_MEMORY_SCOPE_AGENT);
        while (__any(v < t)) {
          __builtin_amdgcn_s_sleep(2);
          v = __hip_atomic_load(&flags[fidx], __ATOMIC_RELAXED, __HIP_MEMORY_SCOPE_AGENT);
        }
        __builtin_amdgcn_fence(__ATOMIC_ACQUIRE, "agent");
      }
      __syncthreads();
      __builtin_amdgcn_fence(__ATOMIC_ACQUIRE, "agent");
      // gather h(t-1) for this (dir,tile): 16KB from L2
      const uint4* hsrc = (const uint4*)hbuf + (size_t)((((t - 1) & 1) * 8) + group) * 1024;
#pragma unroll
      for (int i = 0; i < 4; i++) hA[tid + i * 256] = hsrc[tid + i * 256];
      __syncthreads();
#pragma unroll
      for (int kk = 0; kk < 8; kk++) {
        int k4b = kk * 4 + q;
        uint4 bfr = Wl[k4b * 64 + nloc];
        acc0 = mfma16(hA[k4b * 32 + ln], bfr, acc0);
        acc1 = mfma16(hA[k4b * 32 + 16 + ln], bfr, acc1);
      }
    }
    // gate preactivation: W*h + x_t@w_ih (precomputed) + (b_ih+b_hh)
#pragma unroll
    for (int r = 0; r < 4; r++) {
      gates[(q * 4 + r) * 68 + nloc] = acc0[r] + bf2f(xv[r]) + breg;
      gates[(16 + q * 4 + r) * 68 + nloc] = acc1[r] + bf2f(xv[4 + r]) + breg;
    }
    // prefetch next step's x-gates (consumed next iteration)
    {
      int tn = (t < 255) ? (t + 1) : 255;
      int sgn = dir ? (255 - tn) : tn;
#pragma unroll
      for (int r = 0; r < 4; r++) {
        xv[r] = xgd[(size_t)((xr0 + r) * 256 + sgn) * NG + nglob];
        xv[4 + r] = xgd[(size_t)((xr0 + 16 + r) * 256 + sgn) * NG + nglob];
      }
    }
    __syncthreads();
    // state update (gate order i,f,g,o) for rows ms and ms+16, col j0+js
    float ig0 = gates[ms * 68 + js], fg0 = gates[ms * 68 + 16 + js];
    float gg0 = gates[ms * 68 + 32 + js], og0 = gates[ms * 68 + 48 + js];
    float ig1 = gates[(ms + 16) * 68 + js], fg1 = gates[(ms + 16) * 68 + 16 + js];
    float gg1 = gates[(ms + 16) * 68 + 32 + js], og1 = gates[(ms + 16) * 68 + 48 + js];
    c0 = sigf(fg0) * c0 + sigf(ig0) * tanh_(gg0);
    c1 = sigf(fg1) * c1 + sigf(ig1) * tanh_(gg1);
    float h0 = sigf(og0) * tanh_(c0);
    float h1 = sigf(og1) * tanh_(c1);
    uint16_t hb0 = f2bf(h0), hb1 = f2bf(h1);
    uint16_t* hdst = hbuf + (size_t)(((t & 1) * 8) + group) * 8192;
    hdst[hb_lo] = hb0;
    hdst[hb_hi] = hb1;
    size_t xo = ((size_t)(tile * 32 + ms) * 256 + sg) * 512 + dir * 256 + kj;
    xout[xo] = hb0;
    xout[xo + (size_t)16 * 256 * 512] = hb1;
    __syncthreads();  // all WG stores complete (vmcnt drained) before release
    if (t < 255 && tid == 0) {
      __hip_atomic_store(&flags[fbase + member], t + 1, __ATOMIC_RELEASE,
                         __HIP_MEMORY_SCOPE_AGENT);
    }
  }
}

// ---------------- LayerNorm + projection to 22 tags ----------------
__global__ __launch_bounds__(256) void k_lnproj(
    const uint16_t* __restrict__ x2, const float* __restrict__ ln_g,
    const float* __restrict__ ln_b, const float* __restrict__ w_out,
    const float* __restrict__ b_out, float* __restrict__ feats) {
  const int w = threadIdx.x >> 6, lane = threadIdx.x & 63;
  const int row = blockIdx.x * 4 + w;
  ushort8 xu = __builtin_bit_cast(ushort8, *((const uint4*)(x2 + (size_t)row * 512) + lane));
  float f[8];
  float s = 0.f, ss = 0.f;
#pragma unroll
  for (int j = 0; j < 8; j++) {
    f[j] = bf2f(xu[j]);
    s += f[j];
    ss += f[j] * f[j];
  }
#pragma unroll
  for (int o = 1; o < 64; o <<= 1) {
    s += __shfl_xor(s, o, 64);
    ss += __shfl_xor(ss, o, 64);
  }
  float mu = s * (1.f / 512.f);
  float var = ss * (1.f / 512.f) - mu * mu;
  float rs = rsqrtf(var + 1e-5f);
  const float4 g0 = *(const float4*)(ln_g + lane * 8);
  const float4 g1 = *(const float4*)(ln_g + lane * 8 + 4);
  const float4 bb0 = *(const float4*)(ln_b + lane * 8);
  const float4 bb1 = *(const float4*)(ln_b + lane * 8 + 4);
  float gl[8] = {g0.x, g0.y, g0.z, g0.w, g1.x, g1.y, g1.z, g1.w};
  float bl[8] = {bb0.x, bb0.y, bb0.z, bb0.w, bb1.x, bb1.y, bb1.z, bb1.w};
  float xh[8];
#pragma unroll
  for (int j = 0; j < 8; j++) xh[j] = (f[j] - mu) * rs * gl[j] + bl[j];
  float* fr = feats + (size_t)row * TAGS;
  for (int tg = 0; tg < TAGS; tg++) {
    const float4 w0 = *(const float4*)(w_out + tg * 512 + lane * 8);
    const float4 w1 = *(const float4*)(w_out + tg * 512 + lane * 8 + 4);
    float p = xh[0] * w0.x + xh[1] * w0.y + xh[2] * w0.z + xh[3] * w0.w + xh[4] * w1.x +
              xh[5] * w1.y + xh[6] * w1.z + xh[7] * w1.w;
#pragma unroll
    for (int o = 1; o < 64; o <<= 1) p += __shfl_xor(p, o, 64);
    if (lane == 0) fr[tg] = p + b_out[tg];
  }
}

// ---------------- CRF NLL: one wave per batch row ----------------
__global__ __launch_bounds__(64) void k_crf(
    const float* __restrict__ feats, const float* __restrict__ trans,
    const int* __restrict__ mask, const int* __restrict__ tags, float* __restrict__ out) {
  const int b = blockIdx.x, j = threadIdx.x;
  const bool act = j < TAGS;
  float tcol[TAGS];
#pragma unroll
  for (int i = 0; i < TAGS; i++) tcol[i] = act ? trans[i * TAGS + j] : 0.f;
  const float tstop = act ? trans[j * TAGS + ST_STOP] : 0.f;
  const float* fb = feats + (size_t)b * 256 * TAGS;
  const int* mb = mask + b * 256;
  const int* tb = tags + b * 256;
  float alpha = act ? (tcol[ST_START] + fb[j]) : -1e30f;
  for (int t = 1; t < 256; t++) {
    float vv[TAGS];
    float mx = -1e30f;
#pragma unroll
    for (int i = 0; i < TAGS; i++) {
      float v = __shfl(alpha, i, 64) + tcol[i];
      vv[i] = v;
      mx = fmaxf(mx, v);
    }
    float s = 0.f;
#pragma unroll
    for (int i = 0; i < TAGS; i++) s += __expf(vv[i] - mx);
    float nw = mx + __logf(s) + (act ? fb[t * TAGS + j] : 0.f);
    if (act && mb[t] > 0) alpha = nw;
  }
  float z = act ? (alpha + tstop) : -1e30f;
  float mz = z;
#pragma unroll
  for (int o = 1; o < 64; o <<= 1) mz = fmaxf(mz, __shfl_xor(mz, o, 64));
  float se = act ? __expf(z - mz) : 0.f;
#pragma unroll
  for (int o = 1; o < 64; o <<= 1) se += __shfl_xor(se, o, 64);
  float logZ = mz + __logf(se);
  float em = 0.f;
  int cnt = 0;
  for (int tt = j; tt < 256; tt += 64) {
    int m = mb[tt];
    cnt += m;
    if (m > 0) em += fb[tt * TAGS + tb[tt]];
  }
#pragma unroll
  for (int o = 1; o < 64; o <<= 1) {
    em += __shfl_xor(em, o, 64);
    cnt += __shfl_xor(cnt, o, 64);
  }
  float tr = 0.f;
  for (int tt = 1 + j; tt < 256; tt += 64)
    if (mb[tt] > 0) tr += trans[tb[tt - 1] * TAGS + tb[tt]];
#pragma unroll
  for (int o = 1; o < 64; o <<= 1) tr += __shfl_xor(tr, o, 64);
  if (j == 0) {
    tr += trans[ST_START * TAGS + tb[0]];
    int last = cnt - 1;
    tr += trans[tb[last] * TAGS + ST_STOP];
    atomicAdd(out, (logZ - em - tr) * (1.f / 128.f));
  }
}

extern "C" void kernel_launch(void* const* d_in, const int* in_sizes, int n_in, void* d_out,
                              int out_size, void* d_ws, size_t ws_size, hipStream_t stream) {
  (void)in_sizes;
  (void)n_in;
  const float* emb = (const float*)d_in[0];
  const float* w_ih0 = (const float*)d_in[1];
  const float* w_hh0 = (const float*)d_in[2];
  const float* b_ih0 = (const float*)d_in[3];
  const float* b_hh0 = (const float*)d_in[4];
  const float* w_ih1 = (const float*)d_in[5];
  const float* w_hh1 = (const float*)d_in[6];
  const float* b_ih1 = (const float*)d_in[7];
  const float* b_hh1 = (const float*)d_in[8];
  const float* ln_g = (const float*)d_in[9];
  const float* ln_b = (const float*)d_in[10];
  const float* w_out = (const float*)d_in[11];
  const float* b_out = (const float*)d_in[12];
  const float* trans = (const float*)d_in[13];
  const int* word = (const int*)d_in[14];
  const int* mask = (const int*)d_in[15];
  const int* tags = (const int*)d_in[16];

  char* ws = (char*)d_ws;
  size_t off = 0;
  auto take = [&](size_t bytes) -> char* {
    char* p = ws + off;
    off = (off + bytes + 255) & ~(size_t)255;
    return p;
  };
  uint16_t* wb0 = (uint16_t*)take((size_t)2048 * 256 * 2);
  uint16_t* wb1 = (uint16_t*)take((size_t)2048 * 512 * 2);
  uint16_t* xg = (uint16_t*)take((size_t)2 * BS_ * 1024 * 2);
  uint16_t* x1 = (uint16_t*)take((size_t)BS_ * 512 * 2);
  float* feats = (float*)take((size_t)BS_ * TAGS * 4);
  uint16_t* hbuf = (uint16_t*)take((size_t)2 * 8 * 8192 * 2);
  int* flags = (int*)take(512 * 4);
  if (off > ws_size) return;
  float* out = (float*)d_out;

  hipLaunchKernelGGL(k_init, dim3(1), dim3(256), 0, stream, out, out_size, flags);
  hipLaunchKernelGGL(k_f2bf, dim3(512), dim3(256), 0, stream, w_ih0, wb0, 2048 * 256);
  hipLaunchKernelGGL(k_f2bf, dim3(512), dim3(256), 0, stream, w_ih1, wb1, 2048 * 512);
  // layer 0
  hipLaunchKernelGGL((k_gemm<true, 256>), dim3(4096), dim3(256), 0, stream, emb, word,
                     (const uint16_t*)nullptr, wb0, xg);
  hipLaunchKernelGGL(k_rec, dim3(128), dim3(256), 0, stream, xg, w_hh0, b_ih0, b_hh0, x1, hbuf,
                     flags);
  // layer 1
  hipLaunchKernelGGL((k_gemm<false, 512>), dim3(4096), dim3(256), 0, stream,
                     (const float*)nullptr, (const int*)nullptr, x1, wb1, xg);
  hipLaunchKernelGGL(k_rec, dim3(128), dim3(256), 0, stream, xg, w_hh1, b_ih1, b_hh1, x1, hbuf,
                     flags + 256);
  // head
  hipLaunchKernelGGL(k_lnproj, dim3(8192), dim3(256), 0, stream, x1, ln_g, ln_b, w_out, b_out,
                     feats);
  hipLaunchKernelGGL(k_crf, dim3(128), dim3(64), 0, stream, feats, trans, mask, tags, out);
}

// Round 3
// 2090.442 us; speedup vs baseline: 4.3038x; 2.8892x over previous
//
#include <hip/hip_runtime.h>
#include <stdint.h>

#define DEVINL __device__ __forceinline__

typedef __attribute__((ext_vector_type(8))) __bf16 bf16x8;
typedef __attribute__((ext_vector_type(8))) unsigned short ushort8;
typedef __attribute__((ext_vector_type(4))) float floatx4;

constexpr int E_ = 256;
constexpr int TAGS = 22, ST_START = 20, ST_STOP = 21;
constexpr int B_ = 128, S_ = 256, BS_ = B_ * S_;
constexpr int NG = 1024;  // 4*H

DEVINL uint16_t f2bf(float f) {  // RNE f32->bf16 (no NaN inputs expected)
  uint32_t u = __builtin_bit_cast(uint32_t, f);
  return (uint16_t)((u + 0x7fffu + ((u >> 16) & 1u)) >> 16);
}
DEVINL float bf2f(uint16_t h) {
  uint32_t u = ((uint32_t)h) << 16;
  return __builtin_bit_cast(float, u);
}
DEVINL uint4 pack8(float4 a, float4 b) {
  ushort8 h;
  h[0] = f2bf(a.x); h[1] = f2bf(a.y); h[2] = f2bf(a.z); h[3] = f2bf(a.w);
  h[4] = f2bf(b.x); h[5] = f2bf(b.y); h[6] = f2bf(b.z); h[7] = f2bf(b.w);
  return __builtin_bit_cast(uint4, h);
}
DEVINL floatx4 mfma16(uint4 a, uint4 b, floatx4 c) {
  return __builtin_amdgcn_mfma_f32_16x16x32_bf16(
      __builtin_bit_cast(bf16x8, a), __builtin_bit_cast(bf16x8, b), c, 0, 0, 0);
}
DEVINL float sigf(float x) { return 1.f / (1.f + __expf(-x)); }
DEVINL float tanh_(float x) { return 1.f - 2.f / (__expf(2.f * x) + 1.f); }

// ---------------- init: zero output + sync flags (ws is poisoned 0xAA) ----------
__global__ void k_init(float* out, int out_n, int* flags) {
  int t = threadIdx.x;
  if (t < out_n) out[t] = 0.f;
  for (int i = t; i < 512; i += 256) flags[i] = 0;
}

// ---------------- f32 -> bf16 weight conversion ----------------
__global__ void k_f2bf(const float* __restrict__ src, uint16_t* __restrict__ dst, int n) {
  int i = blockIdx.x * blockDim.x + threadIdx.x;
  int stride = gridDim.x * blockDim.x;
  for (; i < n; i += stride) dst[i] = f2bf(src[i]);
}

// ---------------- xg GEMM: out[m, ng] = A[m,:] . wb[ng,:]  (ng = dir*1024+n) ----
template <bool EMBED, int K>
__global__ __launch_bounds__(256) void k_gemm(
    const float* __restrict__ emb, const int* __restrict__ word,
    const uint16_t* __restrict__ xa, const uint16_t* __restrict__ wb,
    uint16_t* __restrict__ xg) {
  __shared__ uint4 As[8 * 128];  // [k8][m][8] bf16, 16KB
  __shared__ uint4 Bs[8 * 128];  // [k8][n][8] bf16, 16KB
  const int tid = threadIdx.x;
  const int bx = blockIdx.x;
  const int m0 = (bx & 255) << 7;
  const int n0 = (bx >> 8) << 7;
  const int lane = tid & 63, w = tid >> 6;
  const int ln = lane & 15, q = lane >> 4;
  const int wm = w & 1, wn = w >> 1;

  floatx4 acc[4][4];
#pragma unroll
  for (int a = 0; a < 4; a++)
#pragma unroll
    for (int b = 0; b < 4; b++) acc[a][b] = (floatx4){0.f, 0.f, 0.f, 0.f};

  for (int k0 = 0; k0 < K; k0 += 64) {
#pragma unroll
    for (int it = 0; it < 4; it++) {
      int c = tid + it * 256;  // 0..1023
      int k8 = c & 7, r = c >> 3;
      if (EMBED) {
        int row = word[m0 + r];
        const float* sp = emb + (size_t)row * E_ + k0 + k8 * 8;
        float4 f0 = *(const float4*)sp;
        float4 f1 = *(const float4*)(sp + 4);
        As[k8 * 128 + r] = pack8(f0, f1);
      } else {
        As[k8 * 128 + r] = *(const uint4*)(xa + (size_t)(m0 + r) * K + k0 + k8 * 8);
      }
      Bs[k8 * 128 + r] = *(const uint4*)(wb + (size_t)(n0 + r) * K + k0 + k8 * 8);
    }
    __syncthreads();
#pragma unroll
    for (int kk = 0; kk < 2; kk++) {
      const int k4b = kk * 4 + q;
      uint4 af[4], bf[4];
#pragma unroll
      for (int mt = 0; mt < 4; mt++) af[mt] = As[k4b * 128 + wm * 64 + mt * 16 + ln];
#pragma unroll
      for (int nt = 0; nt < 4; nt++) bf[nt] = Bs[k4b * 128 + wn * 64 + nt * 16 + ln];
#pragma unroll
      for (int mt = 0; mt < 4; mt++)
#pragma unroll
        for (int nt = 0; nt < 4; nt++) acc[mt][nt] = mfma16(af[mt], bf[nt], acc[mt][nt]);
    }
    __syncthreads();
  }
#pragma unroll
  for (int mt = 0; mt < 4; mt++) {
    int Rb = m0 + wm * 64 + mt * 16 + q * 4;
#pragma unroll
    for (int nt = 0; nt < 4; nt++) {
      int C = n0 + wn * 64 + nt * 16 + ln;
      size_t base = (size_t)(C >> 10) * ((size_t)BS_ * NG) + (C & 1023);
#pragma unroll
      for (int r = 0; r < 4; r++) xg[base + (size_t)(Rb + r) * NG] = f2bf(acc[mt][nt][r]);
    }
  }
}

// ---------------- BiLSTM recurrence (one layer, both dirs) ----------------
// 128 WGs x 256 thr. group = (dir, batch-tile of 32) -> 8 groups, 16 members each
// owning 16 h-cols (64 gate rows, 32KB LDS). NO cache-wide fences: all cross-WG
// traffic (hbuf h-exchange + epoch flags) uses relaxed agent-scope atomics
// (sc0sc1 cache-bypass ops -> coherent point). Ordering: __syncthreads drains
// vmcnt of the h atomic-stores before tid0's relaxed flag store (hand-built
// release without buffer_wbl2). xout staged in LDS, flushed every 16 steps.
__global__ __launch_bounds__(256) void k_rec(
    const uint16_t* __restrict__ xg, const float* __restrict__ w_hh,
    const float* __restrict__ b_ih, const float* __restrict__ b_hh,
    uint16_t* __restrict__ xout, uint32_t* __restrict__ hbuf,
    int* __restrict__ flags) {
  __shared__ uint4 Wl[32 * 64];           // B-frag layout [k4][n=64], 32KB
  __shared__ uint64_t hA64[2048];         // A-frag [k4b(32)][m(32)] as 2x uint64, 16KB
  __shared__ float gates[32 * 65];        // [m][64 gate cols], stride 65 (bank-clean)
  __shared__ uint32_t xstage[16 * 256];   // [slot(16)][m(32)][jp(8)], 16KB
  __shared__ float bias_s[64];

  const int tid = threadIdx.x;
  const int wg = blockIdx.x;
  const int group = wg & 7, member = wg >> 3;    // 8 groups x 16 members
  const int dir = group & 1, tile = group >> 1;  // 4 tiles of 32 rows
  const int j0 = member * 16;
  const int lane = tid & 63, w = tid >> 6, ln = lane & 15, q = lane >> 4;

  // stage w_hh slice -> LDS (bf16, B-fragment layout). col n -> gate g=n>>4, j=j0+(n&15)
  for (int p = tid; p < 2048; p += 256) {
    int n = p & 63, k4 = p >> 6;
    int row = dir * 1024 + (n >> 4) * 256 + j0 + (n & 15);
    const float* sp = w_hh + (size_t)row * 256 + k4 * 8;
    float4 f0 = *(const float4*)sp;
    float4 f1 = *(const float4*)(sp + 4);
    Wl[k4 * 64 + n] = pack8(f0, f1);
  }
  if (tid < 64) {
    int row = dir * 1024 + (tid >> 4) * 256 + j0 + (tid & 15);
    bias_s[tid] = b_ih[row] + b_hh[row];
  }
  __syncthreads();

  const int nloc = w * 16 + ln;         // gate col 0..63 (gate = w)
  const int nglob = w * 256 + j0 + ln;  // col in [0,1024)
  const float breg = bias_s[nloc];
  const uint16_t* xgd = xg + (size_t)dir * BS_ * NG;

  // state thread: row msr (0..31), col pair (kj0, kj0+1) with kj0 = j0 + 2*jp
  const int msr = tid & 31, jp = tid >> 5;
  const int hstore_idx = msr * 128 + member * 8 + jp;
  const int fbase = group * 32;
  float c0 = 0.f, c1 = 0.f;

  // rows this thread's MFMA accs cover (for xg prefetch)
  const int xr0 = tile * 32 + q * 4;  // acc0 rows xr0..xr0+3 ; acc1 rows +16
  int sg = dir ? 255 : 0;
  uint16_t xv[8];
#pragma unroll
  for (int r = 0; r < 4; r++) {
    xv[r] = xgd[(size_t)((xr0 + r) * 256 + sg) * NG + nglob];
    xv[4 + r] = xgd[(size_t)((xr0 + 16 + r) * 256 + sg) * NG + nglob];
  }

  const uint4* hAv = (const uint4*)hA64;

  for (int t = 0; t < 256; t++) {
    sg = dir ? (255 - t) : t;
    floatx4 acc0 = (floatx4){0.f, 0.f, 0.f, 0.f};
    floatx4 acc1 = (floatx4){0.f, 0.f, 0.f, 0.f};
    if (t > 0) {
      // wait for all members' epoch >= t (h(t-1) published at coherent point)
      if (tid < 64) {
        const int fidx = fbase + (tid & 15);
        int v = __hip_atomic_load(&flags[fidx], __ATOMIC_RELAXED, __HIP_MEMORY_SCOPE_AGENT);
        while (__any(v < t)) {
          __builtin_amdgcn_s_sleep(1);
          v = __hip_atomic_load(&flags[fidx], __ATOMIC_RELAXED, __HIP_MEMORY_SCOPE_AGENT);
        }
      }
      __syncthreads();
      // gather h(t-1): 16KB via relaxed agent atomic loads (coherent point)
      const uint64_t* hsrc =
          (const uint64_t*)hbuf + (size_t)((((t - 1) & 1) * 8) + group) * 2048;
#pragma unroll
      for (int i = 0; i < 8; i++) {
        int p = tid * 8 + i;
        uint64_t v = __hip_atomic_load(&hsrc[p], __ATOMIC_RELAXED, __HIP_MEMORY_SCOPE_AGENT);
        int row = p >> 6, q4 = p & 63;
        hA64[(size_t)((q4 >> 1) * 32 + row) * 2 + (q4 & 1)] = v;
      }
      __syncthreads();
#pragma unroll
      for (int kk = 0; kk < 8; kk++) {
        int k4b = kk * 4 + q;
        uint4 bfr = Wl[k4b * 64 + nloc];
        acc0 = mfma16(hAv[k4b * 32 + ln], bfr, acc0);
        acc1 = mfma16(hAv[k4b * 32 + 16 + ln], bfr, acc1);
      }
    }
    // gate preactivation: W*h + x_t@w_ih (precomputed) + (b_ih+b_hh)
#pragma unroll
    for (int r = 0; r < 4; r++) {
      gates[(q * 4 + r) * 65 + nloc] = acc0[r] + bf2f(xv[r]) + breg;
      gates[(16 + q * 4 + r) * 65 + nloc] = acc1[r] + bf2f(xv[4 + r]) + breg;
    }
    // prefetch next step's x-gates (consumed next iteration)
    {
      int tn = (t < 255) ? (t + 1) : 255;
      int sgn = dir ? (255 - tn) : tn;
#pragma unroll
      for (int r = 0; r < 4; r++) {
        xv[r] = xgd[(size_t)((xr0 + r) * 256 + sgn) * NG + nglob];
        xv[4 + r] = xgd[(size_t)((xr0 + 16 + r) * 256 + sgn) * NG + nglob];
      }
    }
    __syncthreads();
    // state update (gate order i,f,g,o): row msr, cols kj0, kj0+1
    const float* gr = gates + msr * 65 + 2 * jp;
    float ig0 = gr[0], fg0 = gr[16], gg0 = gr[32], og0 = gr[48];
    float ig1 = gr[1], fg1 = gr[17], gg1 = gr[33], og1 = gr[49];
    c0 = sigf(fg0) * c0 + sigf(ig0) * tanh_(gg0);
    c1 = sigf(fg1) * c1 + sigf(ig1) * tanh_(gg1);
    float h0 = sigf(og0) * tanh_(c0);
    float h1 = sigf(og1) * tanh_(c1);
    uint32_t hpack = (uint32_t)f2bf(h0) | ((uint32_t)f2bf(h1) << 16);
    xstage[(t & 15) * 256 + msr * 8 + jp] = hpack;
    if (t < 255) {
      __hip_atomic_store(&hbuf[(size_t)(((t & 1) * 8) + group) * 4096 + hstore_idx], hpack,
                         __ATOMIC_RELAXED, __HIP_MEMORY_SCOPE_AGENT);
    }
    __syncthreads();  // drains vmcnt: h stores ack'd at coherent point; xstage visible
    if (t < 255 && tid == 0) {
      __hip_atomic_store(&flags[fbase + member], t + 1, __ATOMIC_RELAXED,
                         __HIP_MEMORY_SCOPE_AGENT);
    }
    if ((t & 15) == 15) {
      // flush xstage -> xout (plain cached stores; written back lazily / at kernel end)
#pragma unroll
      for (int pp = 0; pp < 2; pp++) {
        int p = tid + pp * 256;
        int m = p & 31, u = p >> 5;  // u 0..15 (pp=0: 0..7, pp=1: 8..15)
        int tt = t - 15 + u;
        int ssg = dir ? (255 - tt) : tt;
        const uint4* src = (const uint4*)(xstage + u * 256 + m * 8);
        uint16_t* dst = xout + ((size_t)(tile * 32 + m) * 256 + ssg) * 512 + dir * 256 + j0;
        ((uint4*)dst)[0] = src[0];
        ((uint4*)dst)[1] = src[1];
      }
      // no extra barrier: slot reuse is >=2 __syncthreads away
    }
  }
}

// ---------------- LayerNorm + projection to 22 tags ----------------
__global__ __launch_bounds__(256) void k_lnproj(
    const uint16_t* __restrict__ x2, const float* __restrict__ ln_g,
    const float* __restrict__ ln_b, const float* __restrict__ w_out,
    const float* __restrict__ b_out, float* __restrict__ feats) {
  const int w = threadIdx.x >> 6, lane = threadIdx.x & 63;
  const int row = blockIdx.x * 4 + w;
  ushort8 xu = __builtin_bit_cast(ushort8, *((const uint4*)(x2 + (size_t)row * 512) + lane));
  float f[8];
  float s = 0.f, ss = 0.f;
#pragma unroll
  for (int j = 0; j < 8; j++) {
    f[j] = bf2f(xu[j]);
    s += f[j];
    ss += f[j] * f[j];
  }
#pragma unroll
  for (int o = 1; o < 64; o <<= 1) {
    s += __shfl_xor(s, o, 64);
    ss += __shfl_xor(ss, o, 64);
  }
  float mu = s * (1.f / 512.f);
  float var = ss * (1.f / 512.f) - mu * mu;
  float rs = rsqrtf(var + 1e-5f);
  const float4 g0 = *(const float4*)(ln_g + lane * 8);
  const float4 g1 = *(const float4*)(ln_g + lane * 8 + 4);
  const float4 bb0 = *(const float4*)(ln_b + lane * 8);
  const float4 bb1 = *(const float4*)(ln_b + lane * 8 + 4);
  float gl[8] = {g0.x, g0.y, g0.z, g0.w, g1.x, g1.y, g1.z, g1.w};
  float bl[8] = {bb0.x, bb0.y, bb0.z, bb0.w, bb1.x, bb1.y, bb1.z, bb1.w};
  float xh[8];
#pragma unroll
  for (int j = 0; j < 8; j++) xh[j] = (f[j] - mu) * rs * gl[j] + bl[j];
  float* fr = feats + (size_t)row * TAGS;
  for (int tg = 0; tg < TAGS; tg++) {
    const float4 w0 = *(const float4*)(w_out + tg * 512 + lane * 8);
    const float4 w1 = *(const float4*)(w_out + tg * 512 + lane * 8 + 4);
    float p = xh[0] * w0.x + xh[1] * w0.y + xh[2] * w0.z + xh[3] * w0.w + xh[4] * w1.x +
              xh[5] * w1.y + xh[6] * w1.z + xh[7] * w1.w;
#pragma unroll
    for (int o = 1; o < 64; o <<= 1) p += __shfl_xor(p, o, 64);
    if (lane == 0) fr[tg] = p + b_out[tg];
  }
}

// ---------------- CRF NLL: one wave per batch row ----------------
__global__ __launch_bounds__(64) void k_crf(
    const float* __restrict__ feats, const float* __restrict__ trans,
    const int* __restrict__ mask, const int* __restrict__ tags, float* __restrict__ out) {
  const int b = blockIdx.x, j = threadIdx.x;
  const bool act = j < TAGS;
  float tcol[TAGS];
#pragma unroll
  for (int i = 0; i < TAGS; i++) tcol[i] = act ? trans[i * TAGS + j] : 0.f;
  const float tstop = act ? trans[j * TAGS + ST_STOP] : 0.f;
  const float* fb = feats + (size_t)b * 256 * TAGS;
  const int* mb = mask + b * 256;
  const int* tb = tags + b * 256;
  float alpha = act ? (tcol[ST_START] + fb[j]) : -1e30f;
  for (int t = 1; t < 256; t++) {
    float vv[TAGS];
    float mx = -1e30f;
#pragma unroll
    for (int i = 0; i < TAGS; i++) {
      float v = __shfl(alpha, i, 64) + tcol[i];
      vv[i] = v;
      mx = fmaxf(mx, v);
    }
    float s = 0.f;
#pragma unroll
    for (int i = 0; i < TAGS; i++) s += __expf(vv[i] - mx);
    float nw = mx + __logf(s) + (act ? fb[t * TAGS + j] : 0.f);
    if (act && mb[t] > 0) alpha = nw;
  }
  float z = act ? (alpha + tstop) : -1e30f;
  float mz = z;
#pragma unroll
  for (int o = 1; o < 64; o <<= 1) mz = fmaxf(mz, __shfl_xor(mz, o, 64));
  float se = act ? __expf(z - mz) : 0.f;
#pragma unroll
  for (int o = 1; o < 64; o <<= 1) se += __shfl_xor(se, o, 64);
  float logZ = mz + __logf(se);
  float em = 0.f;
  int cnt = 0;
  for (int tt = j; tt < 256; tt += 64) {
    int m = mb[tt];
    cnt += m;
    if (m > 0) em += fb[tt * TAGS + tb[tt]];
  }
#pragma unroll
  for (int o = 1; o < 64; o <<= 1) {
    em += __shfl_xor(em, o, 64);
    cnt += __shfl_xor(cnt, o, 64);
  }
  float tr = 0.f;
  for (int tt = 1 + j; tt < 256; tt += 64)
    if (mb[tt] > 0) tr += trans[tb[tt - 1] * TAGS + tb[tt]];
#pragma unroll
  for (int o = 1; o < 64; o <<= 1) tr += __shfl_xor(tr, o, 64);
  if (j == 0) {
    tr += trans[ST_START * TAGS + tb[0]];
    int last = cnt - 1;
    tr += trans[tb[last] * TAGS + ST_STOP];
    atomicAdd(out, (logZ - em - tr) * (1.f / 128.f));
  }
}

extern "C" void kernel_launch(void* const* d_in, const int* in_sizes, int n_in, void* d_out,
                              int out_size, void* d_ws, size_t ws_size, hipStream_t stream) {
  (void)in_sizes;
  (void)n_in;
  const float* emb = (const float*)d_in[0];
  const float* w_ih0 = (const float*)d_in[1];
  const float* w_hh0 = (const float*)d_in[2];
  const float* b_ih0 = (const float*)d_in[3];
  const float* b_hh0 = (const float*)d_in[4];
  const float* w_ih1 = (const float*)d_in[5];
  const float* w_hh1 = (const float*)d_in[6];
  const float* b_ih1 = (const float*)d_in[7];
  const float* b_hh1 = (const float*)d_in[8];
  const float* ln_g = (const float*)d_in[9];
  const float* ln_b = (const float*)d_in[10];
  const float* w_out = (const float*)d_in[11];
  const float* b_out = (const float*)d_in[12];
  const float* trans = (const float*)d_in[13];
  const int* word = (const int*)d_in[14];
  const int* mask = (const int*)d_in[15];
  const int* tags = (const int*)d_in[16];

  char* ws = (char*)d_ws;
  size_t off = 0;
  auto take = [&](size_t bytes) -> char* {
    char* p = ws + off;
    off = (off + bytes + 255) & ~(size_t)255;
    return p;
  };
  uint16_t* wb0 = (uint16_t*)take((size_t)2048 * 256 * 2);
  uint16_t* wb1 = (uint16_t*)take((size_t)2048 * 512 * 2);
  uint16_t* xg = (uint16_t*)take((size_t)2 * BS_ * 1024 * 2);
  uint16_t* x1 = (uint16_t*)take((size_t)BS_ * 512 * 2);
  float* feats = (float*)take((size_t)BS_ * TAGS * 4);
  uint32_t* hbuf = (uint32_t*)take((size_t)2 * 8 * 4096 * 4);
  int* flags = (int*)take(512 * 4);
  if (off > ws_size) return;
  float* out = (float*)d_out;

  hipLaunchKernelGGL(k_init, dim3(1), dim3(256), 0, stream, out, out_size, flags);
  hipLaunchKernelGGL(k_f2bf, dim3(512), dim3(256), 0, stream, w_ih0, wb0, 2048 * 256);
  hipLaunchKernelGGL(k_f2bf, dim3(512), dim3(256), 0, stream, w_ih1, wb1, 2048 * 512);
  // layer 0
  hipLaunchKernelGGL((k_gemm<true, 256>), dim3(4096), dim3(256), 0, stream, emb, word,
                     (const uint16_t*)nullptr, wb0, xg);
  hipLaunchKernelGGL(k_rec, dim3(128), dim3(256), 0, stream, xg, w_hh0, b_ih0, b_hh0, x1, hbuf,
                     flags);
  // layer 1
  hipLaunchKernelGGL((k_gemm<false, 512>), dim3(4096), dim3(256), 0, stream,
                     (const float*)nullptr, (const int*)nullptr, x1, wb1, xg);
  hipLaunchKernelGGL(k_rec, dim3(128), dim3(256), 0, stream, xg, w_hh1, b_ih1, b_hh1, x1, hbuf,
                     flags + 256);
  // head
  hipLaunchKernelGGL(k_lnproj, dim3(8192), dim3(256), 0, stream, x1, ln_g, ln_b, w_out, b_out,
                     feats);
  hipLaunchKernelGGL(k_crf, dim3(128), dim3(64), 0, stream, feats, trans, mask, tags, out);
}

// Round 4
// 1645.781 us; speedup vs baseline: 5.4667x; 1.2702x over previous
//
#include <hip/hip_runtime.h>
#include <stdint.h>

#define DEVINL __device__ __forceinline__

typedef __attribute__((ext_vector_type(8))) __bf16 bf16x8;
typedef __attribute__((ext_vector_type(8))) unsigned short ushort8;
typedef __attribute__((ext_vector_type(4))) float floatx4;

constexpr int E_ = 256;
constexpr int TAGS = 22, ST_START = 20, ST_STOP = 21;
constexpr int B_ = 128, S_ = 256, BS_ = B_ * S_;
constexpr int NG = 1024;  // 4*H

DEVINL uint16_t f2bf(float f) {  // RNE f32->bf16 (no NaN inputs expected)
  uint32_t u = __builtin_bit_cast(uint32_t, f);
  return (uint16_t)((u + 0x7fffu + ((u >> 16) & 1u)) >> 16);
}
DEVINL float bf2f(uint16_t h) {
  uint32_t u = ((uint32_t)h) << 16;
  return __builtin_bit_cast(float, u);
}
DEVINL uint4 pack8(float4 a, float4 b) {
  ushort8 h;
  h[0] = f2bf(a.x); h[1] = f2bf(a.y); h[2] = f2bf(a.z); h[3] = f2bf(a.w);
  h[4] = f2bf(b.x); h[5] = f2bf(b.y); h[6] = f2bf(b.z); h[7] = f2bf(b.w);
  return __builtin_bit_cast(uint4, h);
}
DEVINL floatx4 mfma16(uint4 a, uint4 b, floatx4 c) {
  return __builtin_amdgcn_mfma_f32_16x16x32_bf16(
      __builtin_bit_cast(bf16x8, a), __builtin_bit_cast(bf16x8, b), c, 0, 0, 0);
}
DEVINL float sigf(float x) { return 1.f / (1.f + __expf(-x)); }
DEVINL float tanh_(float x) { return 1.f - 2.f / (__expf(2.f * x) + 1.f); }

// ---------------- init: zero output (ws is poisoned 0xAA) ----------
__global__ void k_init(float* out, int out_n) {
  int t = threadIdx.x;
  if (t < out_n) out[t] = 0.f;
}

// ---------------- f32 -> bf16 weight conversion ----------------
__global__ void k_f2bf(const float* __restrict__ src, uint16_t* __restrict__ dst, int n) {
  int i = blockIdx.x * blockDim.x + threadIdx.x;
  int stride = gridDim.x * blockDim.x;
  for (; i < n; i += stride) dst[i] = f2bf(src[i]);
}

// ---------------- xg GEMM: out[m, ng] = A[m,:] . wb[ng,:]  (ng = dir*1024+n) ----
template <bool EMBED, int K>
__global__ __launch_bounds__(256) void k_gemm(
    const float* __restrict__ emb, const int* __restrict__ word,
    const uint16_t* __restrict__ xa, const uint16_t* __restrict__ wb,
    uint16_t* __restrict__ xg) {
  __shared__ uint4 As[8 * 128];  // [k8][m][8] bf16, 16KB
  __shared__ uint4 Bs[8 * 128];  // [k8][n][8] bf16, 16KB
  const int tid = threadIdx.x;
  const int bx = blockIdx.x;
  const int m0 = (bx & 255) << 7;
  const int n0 = (bx >> 8) << 7;
  const int lane = tid & 63, w = tid >> 6;
  const int ln = lane & 15, q = lane >> 4;
  const int wm = w & 1, wn = w >> 1;

  floatx4 acc[4][4];
#pragma unroll
  for (int a = 0; a < 4; a++)
#pragma unroll
    for (int b = 0; b < 4; b++) acc[a][b] = (floatx4){0.f, 0.f, 0.f, 0.f};

  for (int k0 = 0; k0 < K; k0 += 64) {
#pragma unroll
    for (int it = 0; it < 4; it++) {
      int c = tid + it * 256;  // 0..1023
      int k8 = c & 7, r = c >> 3;
      if (EMBED) {
        int row = word[m0 + r];
        const float* sp = emb + (size_t)row * E_ + k0 + k8 * 8;
        float4 f0 = *(const float4*)sp;
        float4 f1 = *(const float4*)(sp + 4);
        As[k8 * 128 + r] = pack8(f0, f1);
      } else {
        As[k8 * 128 + r] = *(const uint4*)(xa + (size_t)(m0 + r) * K + k0 + k8 * 8);
      }
      Bs[k8 * 128 + r] = *(const uint4*)(wb + (size_t)(n0 + r) * K + k0 + k8 * 8);
    }
    __syncthreads();
#pragma unroll
    for (int kk = 0; kk < 2; kk++) {
      const int k4b = kk * 4 + q;
      uint4 af[4], bf[4];
#pragma unroll
      for (int mt = 0; mt < 4; mt++) af[mt] = As[k4b * 128 + wm * 64 + mt * 16 + ln];
#pragma unroll
      for (int nt = 0; nt < 4; nt++) bf[nt] = Bs[k4b * 128 + wn * 64 + nt * 16 + ln];
#pragma unroll
      for (int mt = 0; mt < 4; mt++)
#pragma unroll
        for (int nt = 0; nt < 4; nt++) acc[mt][nt] = mfma16(af[mt], bf[nt], acc[mt][nt]);
    }
    __syncthreads();
  }
#pragma unroll
  for (int mt = 0; mt < 4; mt++) {
    int Rb = m0 + wm * 64 + mt * 16 + q * 4;
#pragma unroll
    for (int nt = 0; nt < 4; nt++) {
      int C = n0 + wn * 64 + nt * 16 + ln;
      size_t base = (size_t)(C >> 10) * ((size_t)BS_ * NG) + (C & 1023);
#pragma unroll
      for (int r = 0; r < 4; r++) xg[base + (size_t)(Rb + r) * NG] = f2bf(acc[mt][nt][r]);
    }
  }
}

// ---------------- BiLSTM recurrence (one layer, both dirs) ----------------
// 128 WGs x 256 thr. group = (dir, batch-tile of 32) -> 8 groups, 16 members each
// owning 16 h-cols (64 gate rows, 32KB LDS weights). Cross-WG h exchange:
// epoch-stamped 8B entries {epoch(hi32) | hpack(lo32)} at the coherent point via
// relaxed agent atomics -- data carries its own flag, ONE round-trip per step.
// hbuf entry order == flattened LDS A-frag order: e = (cp>>2)*128 + m*4 + (cp&3)
// so readers load e = tid+256*i (coalesced) and LDS-write conflict-free.
__global__ __launch_bounds__(256) void k_rec(
    const uint16_t* __restrict__ xg, const float* __restrict__ w_hh,
    const float* __restrict__ b_ih, const float* __restrict__ b_hh,
    uint16_t* __restrict__ xout, uint64_t* __restrict__ hbuf, int ebase) {
  __shared__ uint4 Wl[32 * 64];          // B-frag layout [k4][n=64], 32KB
  __shared__ uint32_t hA32[4096];        // A-frag [k4b(32)][m(32)][c(4)] u32, 16KB
  __shared__ float gates[32 * 66];       // [m][64 gate cols], stride 66 (bank-spread)
  __shared__ uint32_t xstage[16 * 256];  // [slot(16)][jp(8)][msr(32)], 16KB
  __shared__ float bias_s[64];

  const int tid = threadIdx.x;
  const int wg = blockIdx.x;
  const int group = wg & 7, member = wg >> 3;    // 8 groups x 16 members
  const int dir = group & 1, tile = group >> 1;  // 4 tiles of 32 rows
  const int j0 = member * 16;
  const int lane = tid & 63, w = tid >> 6, ln = lane & 15, q = lane >> 4;

  // stage w_hh slice -> LDS (bf16, B-fragment layout). col n -> gate g=n>>4, j=j0+(n&15)
  for (int p = tid; p < 2048; p += 256) {
    int n = p & 63, k4 = p >> 6;
    int row = dir * 1024 + (n >> 4) * 256 + j0 + (n & 15);
    const float* sp = w_hh + (size_t)row * 256 + k4 * 8;
    float4 f0 = *(const float4*)sp;
    float4 f1 = *(const float4*)(sp + 4);
    Wl[k4 * 64 + n] = pack8(f0, f1);
  }
  if (tid < 64) {
    int row = dir * 1024 + (tid >> 4) * 256 + j0 + (tid & 15);
    bias_s[tid] = b_ih[row] + b_hh[row];
  }
  __syncthreads();

  const int nloc = w * 16 + ln;         // gate col 0..63 (gate = w)
  const int nglob = w * 256 + j0 + ln;  // col in [0,1024)
  const float breg = bias_s[nloc];
  const uint16_t* xgd = xg + (size_t)dir * BS_ * NG;

  // state thread: row msr (0..31), col pair cp = member*8 + jp (cols 2cp, 2cp+1)
  const int msr = tid & 31, jp = tid >> 5;
  const int cp = member * 8 + jp;
  const int e_pub = (cp >> 2) * 128 + msr * 4 + (cp & 3);  // A-frag-flattened entry
  float c0 = 0.f, c1 = 0.f;

  // rows this thread's MFMA accs cover (for xg prefetch)
  const int xr0 = tile * 32 + q * 4;  // acc0 rows xr0..xr0+3 ; acc1 rows +16
  int sg = dir ? 255 : 0;
  uint16_t xv[8];
#pragma unroll
  for (int r = 0; r < 4; r++) {
    xv[r] = xgd[(size_t)((xr0 + r) * 256 + sg) * NG + nglob];
    xv[4 + r] = xgd[(size_t)((xr0 + 16 + r) * 256 + sg) * NG + nglob];
  }

  const uint4* hAv = (const uint4*)hA32;

  for (int t = 0; t < 256; t++) {
    sg = dir ? (255 - t) : t;
    floatx4 acc0 = (floatx4){0.f, 0.f, 0.f, 0.f};
    floatx4 acc1 = (floatx4){0.f, 0.f, 0.f, 0.f};
    if (t > 0) {
      // gather h(t-1): 4096 epoch-stamped entries; poll data until epoch fresh
      const uint64_t* hsrc = hbuf + (size_t)((((t - 1) & 1) * 8) + group) * 4096;
      const uint32_t want = (uint32_t)(ebase + t);
      uint64_t v[16];
#pragma unroll
      for (int i = 0; i < 16; i++)
        v[i] = __hip_atomic_load(&hsrc[tid + 256 * i], __ATOMIC_RELAXED,
                                 __HIP_MEMORY_SCOPE_AGENT);
#pragma unroll
      for (int i = 0; i < 16; i++) {
        while ((uint32_t)(v[i] >> 32) != want) {
          __builtin_amdgcn_s_sleep(1);
          v[i] = __hip_atomic_load(&hsrc[tid + 256 * i], __ATOMIC_RELAXED,
                                   __HIP_MEMORY_SCOPE_AGENT);
        }
      }
#pragma unroll
      for (int i = 0; i < 16; i++) hA32[tid + 256 * i] = (uint32_t)v[i];
      __syncthreads();
#pragma unroll
      for (int kk = 0; kk < 8; kk++) {
        int k4b = kk * 4 + q;
        uint4 bfr = Wl[k4b * 64 + nloc];
        acc0 = mfma16(hAv[k4b * 32 + ln], bfr, acc0);
        acc1 = mfma16(hAv[k4b * 32 + 16 + ln], bfr, acc1);
      }
    }
    // gate preactivation: W*h + x_t@w_ih (precomputed) + (b_ih+b_hh)
#pragma unroll
    for (int r = 0; r < 4; r++) {
      gates[(q * 4 + r) * 66 + nloc] = acc0[r] + bf2f(xv[r]) + breg;
      gates[(16 + q * 4 + r) * 66 + nloc] = acc1[r] + bf2f(xv[4 + r]) + breg;
    }
    // prefetch next step's x-gates (consumed next iteration)
    {
      int tn = (t < 255) ? (t + 1) : 255;
      int sgn = dir ? (255 - tn) : tn;
#pragma unroll
      for (int r = 0; r < 4; r++) {
        xv[r] = xgd[(size_t)((xr0 + r) * 256 + sgn) * NG + nglob];
        xv[4 + r] = xgd[(size_t)((xr0 + 16 + r) * 256 + sgn) * NG + nglob];
      }
    }
    __syncthreads();
    // state update (gate order i,f,g,o): row msr, cols 2cp, 2cp+1
    const float* gr = gates + msr * 66 + 2 * jp;
    float ig0 = gr[0], fg0 = gr[16], gg0 = gr[32], og0 = gr[48];
    float ig1 = gr[1], fg1 = gr[17], gg1 = gr[33], og1 = gr[49];
    c0 = sigf(fg0) * c0 + sigf(ig0) * tanh_(gg0);
    c1 = sigf(fg1) * c1 + sigf(ig1) * tanh_(gg1);
    float h0 = sigf(og0) * tanh_(c0);
    float h1 = sigf(og1) * tanh_(c1);
    uint32_t hpack = (uint32_t)f2bf(h0) | ((uint32_t)f2bf(h1) << 16);
    xstage[(t & 15) * 256 + jp * 32 + msr] = hpack;
    if (t < 255) {
      uint64_t pk = (uint64_t)hpack | ((uint64_t)(uint32_t)(ebase + t + 1) << 32);
      __hip_atomic_store(&hbuf[(size_t)(((t & 1) * 8) + group) * 4096 + e_pub], pk,
                         __ATOMIC_RELAXED, __HIP_MEMORY_SCOPE_AGENT);
    }
    if ((t & 15) == 15) {
      __syncthreads();  // all xstage writes for slots t-15..t visible
#pragma unroll
      for (int pp = 0; pp < 2; pp++) {
        int p = tid + pp * 256;
        int m = p & 31, u = p >> 5;  // u 0..15
        int tt = t - 15 + u;
        int ssg = dir ? (255 - tt) : tt;
        uint32_t d[8];
#pragma unroll
        for (int jj = 0; jj < 8; jj++) d[jj] = xstage[u * 256 + jj * 32 + m];
        uint16_t* dst = xout + ((size_t)(tile * 32 + m) * 256 + ssg) * 512 + dir * 256 + j0;
        ((uint4*)dst)[0] = (uint4){d[0], d[1], d[2], d[3]};
        ((uint4*)dst)[1] = (uint4){d[4], d[5], d[6], d[7]};
      }
    }
  }
}

// ---------------- LayerNorm + projection to 22 tags ----------------
__global__ __launch_bounds__(256) void k_lnproj(
    const uint16_t* __restrict__ x2, const float* __restrict__ ln_g,
    const float* __restrict__ ln_b, const float* __restrict__ w_out,
    const float* __restrict__ b_out, float* __restrict__ feats) {
  const int w = threadIdx.x >> 6, lane = threadIdx.x & 63;
  const int row = blockIdx.x * 4 + w;
  ushort8 xu = __builtin_bit_cast(ushort8, *((const uint4*)(x2 + (size_t)row * 512) + lane));
  float f[8];
  float s = 0.f, ss = 0.f;
#pragma unroll
  for (int j = 0; j < 8; j++) {
    f[j] = bf2f(xu[j]);
    s += f[j];
    ss += f[j] * f[j];
  }
#pragma unroll
  for (int o = 1; o < 64; o <<= 1) {
    s += __shfl_xor(s, o, 64);
    ss += __shfl_xor(ss, o, 64);
  }
  float mu = s * (1.f / 512.f);
  float var = ss * (1.f / 512.f) - mu * mu;
  float rs = rsqrtf(var + 1e-5f);
  const float4 g0 = *(const float4*)(ln_g + lane * 8);
  const float4 g1 = *(const float4*)(ln_g + lane * 8 + 4);
  const float4 bb0 = *(const float4*)(ln_b + lane * 8);
  const float4 bb1 = *(const float4*)(ln_b + lane * 8 + 4);
  float gl[8] = {g0.x, g0.y, g0.z, g0.w, g1.x, g1.y, g1.z, g1.w};
  float bl[8] = {bb0.x, bb0.y, bb0.z, bb0.w, bb1.x, bb1.y, bb1.z, bb1.w};
  float xh[8];
#pragma unroll
  for (int j = 0; j < 8; j++) xh[j] = (f[j] - mu) * rs * gl[j] + bl[j];
  float* fr = feats + (size_t)row * TAGS;
  for (int tg = 0; tg < TAGS; tg++) {
    const float4 w0 = *(const float4*)(w_out + tg * 512 + lane * 8);
    const float4 w1 = *(const float4*)(w_out + tg * 512 + lane * 8 + 4);
    float p = xh[0] * w0.x + xh[1] * w0.y + xh[2] * w0.z + xh[3] * w0.w + xh[4] * w1.x +
              xh[5] * w1.y + xh[6] * w1.z + xh[7] * w1.w;
#pragma unroll
    for (int o = 1; o < 64; o <<= 1) p += __shfl_xor(p, o, 64);
    if (lane == 0) fr[tg] = p + b_out[tg];
  }
}

// ---------------- CRF NLL: one wave per batch row ----------------
__global__ __launch_bounds__(64) void k_crf(
    const float* __restrict__ feats, const float* __restrict__ trans,
    const int* __restrict__ mask, const int* __restrict__ tags, float* __restrict__ out) {
  const int b = blockIdx.x, j = threadIdx.x;
  const bool act = j < TAGS;
  float tcol[TAGS];
#pragma unroll
  for (int i = 0; i < TAGS; i++) tcol[i] = act ? trans[i * TAGS + j] : 0.f;
  const float tstop = act ? trans[j * TAGS + ST_STOP] : 0.f;
  const float* fb = feats + (size_t)b * 256 * TAGS;
  const int* mb = mask + b * 256;
  const int* tb = tags + b * 256;
  float alpha = act ? (tcol[ST_START] + fb[j]) : -1e30f;
  for (int t = 1; t < 256; t++) {
    float vv[TAGS];
    float mx = -1e30f;
#pragma unroll
    for (int i = 0; i < TAGS; i++) {
      float v = __shfl(alpha, i, 64) + tcol[i];
      vv[i] = v;
      mx = fmaxf(mx, v);
    }
    float s = 0.f;
#pragma unroll
    for (int i = 0; i < TAGS; i++) s += __expf(vv[i] - mx);
    float nw = mx + __logf(s) + (act ? fb[t * TAGS + j] : 0.f);
    if (act && mb[t] > 0) alpha = nw;
  }
  float z = act ? (alpha + tstop) : -1e30f;
  float mz = z;
#pragma unroll
  for (int o = 1; o < 64; o <<= 1) mz = fmaxf(mz, __shfl_xor(mz, o, 64));
  float se = act ? __expf(z - mz) : 0.f;
#pragma unroll
  for (int o = 1; o < 64; o <<= 1) se += __shfl_xor(se, o, 64);
  float logZ = mz + __logf(se);
  float em = 0.f;
  int cnt = 0;
  for (int tt = j; tt < 256; tt += 64) {
    int m = mb[tt];
    cnt += m;
    if (m > 0) em += fb[tt * TAGS + tb[tt]];
  }
#pragma unroll
  for (int o = 1; o < 64; o <<= 1) {
    em += __shfl_xor(em, o, 64);
    cnt += __shfl_xor(cnt, o, 64);
  }
  float tr = 0.f;
  for (int tt = 1 + j; tt < 256; tt += 64)
    if (mb[tt] > 0) tr += trans[tb[tt - 1] * TAGS + tb[tt]];
#pragma unroll
  for (int o = 1; o < 64; o <<= 1) tr += __shfl_xor(tr, o, 64);
  if (j == 0) {
    tr += trans[ST_START * TAGS + tb[0]];
    int last = cnt - 1;
    tr += trans[tb[last] * TAGS + ST_STOP];
    atomicAdd(out, (logZ - em - tr) * (1.f / 128.f));
  }
}

extern "C" void kernel_launch(void* const* d_in, const int* in_sizes, int n_in, void* d_out,
                              int out_size, void* d_ws, size_t ws_size, hipStream_t stream) {
  (void)in_sizes;
  (void)n_in;
  const float* emb = (const float*)d_in[0];
  const float* w_ih0 = (const float*)d_in[1];
  const float* w_hh0 = (const float*)d_in[2];
  const float* b_ih0 = (const float*)d_in[3];
  const float* b_hh0 = (const float*)d_in[4];
  const float* w_ih1 = (const float*)d_in[5];
  const float* w_hh1 = (const float*)d_in[6];
  const float* b_ih1 = (const float*)d_in[7];
  const float* b_hh1 = (const float*)d_in[8];
  const float* ln_g = (const float*)d_in[9];
  const float* ln_b = (const float*)d_in[10];
  const float* w_out = (const float*)d_in[11];
  const float* b_out = (const float*)d_in[12];
  const float* trans = (const float*)d_in[13];
  const int* word = (const int*)d_in[14];
  const int* mask = (const int*)d_in[15];
  const int* tags = (const int*)d_in[16];

  char* ws = (char*)d_ws;
  size_t off = 0;
  auto take = [&](size_t bytes) -> char* {
    char* p = ws + off;
    off = (off + bytes + 255) & ~(size_t)255;
    return p;
  };
  uint16_t* wb0 = (uint16_t*)take((size_t)2048 * 256 * 2);
  uint16_t* wb1 = (uint16_t*)take((size_t)2048 * 512 * 2);
  uint16_t* xg = (uint16_t*)take((size_t)2 * BS_ * 1024 * 2);
  uint16_t* x1 = (uint16_t*)take((size_t)BS_ * 512 * 2);
  float* feats = (float*)take((size_t)BS_ * TAGS * 4);
  uint64_t* hbuf = (uint64_t*)take((size_t)2 * 8 * 4096 * 8);
  if (off > ws_size) return;
  float* out = (float*)d_out;

  hipLaunchKernelGGL(k_init, dim3(1), dim3(256), 0, stream, out, out_size);
  hipLaunchKernelGGL(k_f2bf, dim3(512), dim3(256), 0, stream, w_ih0, wb0, 2048 * 256);
  hipLaunchKernelGGL(k_f2bf, dim3(512), dim3(256), 0, stream, w_ih1, wb1, 2048 * 512);
  // layer 0
  hipLaunchKernelGGL((k_gemm<true, 256>), dim3(4096), dim3(256), 0, stream, emb, word,
                     (const uint16_t*)nullptr, wb0, xg);
  hipLaunchKernelGGL(k_rec, dim3(128), dim3(256), 0, stream, xg, w_hh0, b_ih0, b_hh0, x1, hbuf,
                     0);
  // layer 1
  hipLaunchKernelGGL((k_gemm<false, 512>), dim3(4096), dim3(256), 0, stream,
                     (const float*)nullptr, (const int*)nullptr, x1, wb1, xg);
  hipLaunchKernelGGL(k_rec, dim3(128), dim3(256), 0, stream, xg, w_hh1, b_ih1, b_hh1, x1, hbuf,
                     256);
  // head
  hipLaunchKernelGGL(k_lnproj, dim3(8192), dim3(256), 0, stream, x1, ln_g, ln_b, w_out, b_out,
                     feats);
  hipLaunchKernelGGL(k_crf, dim3(128), dim3(64), 0, stream, feats, trans, mask, tags, out);
}